// Round 3
// baseline (751.707 us; speedup 1.0000x reference)
//
#include <hip/hip_runtime.h>

// EdgeSAGELayer: out = relu(concat(node_attr, scatter_mean(edge_attr*ew, tgt)) @ W.T + b) * nw
//
// Sizes (from reference): N=100000 nodes, E=1250000 edges, F=64 edge feats,
// IN=128 node feats, OUT=128. All f32 except edge_index (int32).

#define EF 64
#define IN_CH 128
#define OUT_CH 128
#define K_TOT 192        // IN_CH + EF

// ---------------------------------------------------------------------------
// Kernel 1: scatter-add of weighted edge features + degree count.
// One wave (64 lanes) per edge; lane i handles feature i (coalesced 256B read).
// ---------------------------------------------------------------------------
__global__ __launch_bounds__(256) void edge_scatter_kernel(
    const int* __restrict__ tgt,          // edge_index row 0, [E]
    const float* __restrict__ edge_attr,  // [E, 64]
    const float* __restrict__ edge_weight,// [E]
    float* __restrict__ seg,              // [N, 64] accumulators (pre-zeroed)
    float* __restrict__ cnt,              // [N] degree (pre-zeroed)
    int E)
{
    const int wave = (blockIdx.x * blockDim.x + threadIdx.x) >> 6;
    const int lane = threadIdx.x & 63;
    if (wave >= E) return;

    const int t = tgt[wave];                    // wave-uniform
    const float ew = edge_weight[wave];         // wave-uniform
    const float v = edge_attr[(size_t)wave * EF + lane] * ew;

    atomicAdd(&seg[(size_t)t * EF + lane], v);  // 64 consecutive f32 atomics/wave
    if (lane == 0) atomicAdd(&cnt[t], 1.0f);
}

// ---------------------------------------------------------------------------
// Kernel 2: per-node GEMM + epilogue.
//   h = [node_attr | seg/max(cnt,1)]  (K=192)
//   out = relu(h @ W.T + b) * node_weight
// Block = 256 threads, 64 nodes/block. Thread computes 4 nodes x 8 outputs.
//
// W tile staged in LDS with chunk-permuted k-rows:
//   pos(o) = (o>>3)*4 + (o&3) + ((o&4) ? 64 : 0)
// so the compute-phase ds_read_b128 at [k*128 + c*4] (c = tid&15) sees 16
// distinct addresses at 16B stride spanning 256B => 2 lanes/bank = free
// (vs 32B stride in the naive [k][o] layout => 4-way conflict, 1.58x).
// h tile staged [k][node] with pitch 68 (reads are 4-lane broadcasts, free).
// ---------------------------------------------------------------------------
#define NB 64            // nodes per block
#define KT 64            // k-tile (3 tiles: node_attr k0=0,64; edge_mean k0=128)
#define HP 68            // h_lds pitch (padded, multiple of 4 for float4 align)

__device__ __forceinline__ int wpos(int o) {
    return ((o >> 3) << 2) + (o & 3) + ((o & 4) ? 64 : 0);
}

__global__ __launch_bounds__(256) void node_gemm_kernel(
    const float* __restrict__ node_attr,   // [N, 128]
    const float* __restrict__ seg,         // [N, 64]
    const float* __restrict__ cnt,         // [N]
    const float* __restrict__ W,           // [128, 192] row-major [out][in]
    const float* __restrict__ b,           // [128]
    const float* __restrict__ node_weight, // [N]
    float* __restrict__ out,               // [N, 128]
    int N)
{
    __shared__ float W_lds[KT * OUT_CH];   // [k][pos(o)], 32 KB
    __shared__ float h_lds[KT * HP];       // [k][node], 17 KB

    const int tid   = threadIdx.x;
    const int node0 = blockIdx.x * NB;

    // compute assignment: 16 o-groups x 16 node-groups
    const int oc = tid & 15;               // chunk index; outputs oc*8 .. oc*8+7
    const int o0 = oc * 8;
    const int n0 = (tid >> 4) * 4;         // 4 consecutive (block-local) nodes

    // h staging: thread loads node tid>>2, k-range (tid&3)*16 .. +16
    const int s_node = tid >> 2;
    const int s_k0   = (tid & 3) * 16;
    // W staging: thread loads o = tid&127, k-half (tid>>7)*32 .. +32
    const int w_o    = tid & 127;
    const int w_kh   = (tid >> 7) * 32;
    const int w_p    = wpos(w_o);          // permuted column position

    float acc[4][8];
#pragma unroll
    for (int n = 0; n < 4; ++n)
#pragma unroll
        for (int j = 0; j < 8; ++j) acc[n][j] = 0.0f;

    const int gs_node = node0 + s_node;

    for (int kt = 0; kt < 3; ++kt) {
        const int k0 = kt * KT;
        __syncthreads();

        // ---- stage W tile (permuted-transposed): W_lds[k][wpos(o)] = W[o][k0+k] ----
        {
            const float* src = W + (size_t)w_o * K_TOT + k0 + w_kh;
#pragma unroll
            for (int i = 0; i < 32; i += 4) {
                const float4 wv = *reinterpret_cast<const float4*>(src + i);
                W_lds[(w_kh + i + 0) * OUT_CH + w_p] = wv.x;
                W_lds[(w_kh + i + 1) * OUT_CH + w_p] = wv.y;
                W_lds[(w_kh + i + 2) * OUT_CH + w_p] = wv.z;
                W_lds[(w_kh + i + 3) * OUT_CH + w_p] = wv.w;
            }
        }

        // ---- stage h tile: h_lds[k][node] ----
        if (gs_node < N) {
            if (kt < 2) {
                const float* src = node_attr + (size_t)gs_node * IN_CH + k0 + s_k0;
#pragma unroll
                for (int i = 0; i < 16; i += 4) {
                    const float4 hv = *reinterpret_cast<const float4*>(src + i);
                    h_lds[(s_k0 + i + 0) * HP + s_node] = hv.x;
                    h_lds[(s_k0 + i + 1) * HP + s_node] = hv.y;
                    h_lds[(s_k0 + i + 2) * HP + s_node] = hv.z;
                    h_lds[(s_k0 + i + 3) * HP + s_node] = hv.w;
                }
            } else {
                const float inv = 1.0f / fmaxf(cnt[gs_node], 1.0f);
                const float* src = seg + (size_t)gs_node * EF + s_k0;
#pragma unroll
                for (int i = 0; i < 16; i += 4) {
                    const float4 sv = *reinterpret_cast<const float4*>(src + i);
                    h_lds[(s_k0 + i + 0) * HP + s_node] = sv.x * inv;
                    h_lds[(s_k0 + i + 1) * HP + s_node] = sv.y * inv;
                    h_lds[(s_k0 + i + 2) * HP + s_node] = sv.z * inv;
                    h_lds[(s_k0 + i + 3) * HP + s_node] = sv.w * inv;
                }
            }
        }
        __syncthreads();

        // ---- compute: 32 FMAs per k per thread ----
#pragma unroll 4
        for (int k = 0; k < KT; ++k) {
            const float4 hv = *reinterpret_cast<const float4*>(&h_lds[k * HP + n0]);
            // w0: chunk A_oc at k*128 + oc*4 ; w1: chunk B_oc at k*128 + 64 + oc*4
            const float4 w0 = *reinterpret_cast<const float4*>(&W_lds[k * OUT_CH + oc * 4]);
            const float4 w1 = *reinterpret_cast<const float4*>(&W_lds[k * OUT_CH + 64 + oc * 4]);
            const float hh[4] = {hv.x, hv.y, hv.z, hv.w};
            const float ww[8] = {w0.x, w0.y, w0.z, w0.w, w1.x, w1.y, w1.z, w1.w};
#pragma unroll
            for (int n = 0; n < 4; ++n)
#pragma unroll
                for (int j = 0; j < 8; ++j)
                    acc[n][j] = fmaf(hh[n], ww[j], acc[n][j]);
        }
    }

    // ---- epilogue: bias + relu + node_weight scale ----
    const float4 b0 = *reinterpret_cast<const float4*>(b + o0);
    const float4 b1 = *reinterpret_cast<const float4*>(b + o0 + 4);
    const float bb[8] = {b0.x, b0.y, b0.z, b0.w, b1.x, b1.y, b1.z, b1.w};

#pragma unroll
    for (int n = 0; n < 4; ++n) {
        const int gn = node0 + n0 + n;
        if (gn < N) {
            const float nw = node_weight[gn];
            float r[8];
#pragma unroll
            for (int j = 0; j < 8; ++j)
                r[j] = fmaxf(acc[n][j] + bb[j], 0.0f) * nw;
            float* dst = out + (size_t)gn * OUT_CH + o0;
            *reinterpret_cast<float4*>(dst)     = make_float4(r[0], r[1], r[2], r[3]);
            *reinterpret_cast<float4*>(dst + 4) = make_float4(r[4], r[5], r[6], r[7]);
        }
    }
}

// ---------------------------------------------------------------------------
extern "C" void kernel_launch(void* const* d_in, const int* in_sizes, int n_in,
                              void* d_out, int out_size, void* d_ws, size_t ws_size,
                              hipStream_t stream) {
    const int*   edge_index  = (const int*)d_in[0];   // [2, E], row 0 = targets
    const float* edge_attr   = (const float*)d_in[1]; // [E, 64]
    const float* node_attr   = (const float*)d_in[2]; // [N, 128]
    const float* edge_weight = (const float*)d_in[3]; // [E]
    const float* node_weight = (const float*)d_in[4]; // [N]
    const float* W           = (const float*)d_in[5]; // [128, 192]
    const float* b           = (const float*)d_in[6]; // [128]
    float* out = (float*)d_out;

    const int E = in_sizes[0] / 2;
    const int N = in_sizes[2] / IN_CH;

    float* seg = (float*)d_ws;           // [N, 64]
    float* cnt = seg + (size_t)N * EF;   // [N]
    const size_t zero_bytes = (size_t)N * EF * sizeof(float) + (size_t)N * sizeof(float);

    hipMemsetAsync(d_ws, 0, zero_bytes, stream);

    // scatter: 4 edges per 256-thread block (1 wave per edge)
    const int scatter_blocks = (E + 3) / 4;
    edge_scatter_kernel<<<scatter_blocks, 256, 0, stream>>>(
        edge_index, edge_attr, edge_weight, seg, cnt, E);

    // gemm: 64 nodes per block
    const int gemm_blocks = (N + NB - 1) / NB;
    node_gemm_kernel<<<gemm_blocks, 256, 0, stream>>>(
        node_attr, seg, cnt, W, b, node_weight, out, N);
}